// Round 3
// baseline (690.977 us; speedup 1.0000x reference)
//
#include <hip/hip_runtime.h>

#define NB 64
#define NT 4096
#define CH 16
#define KC (NT/CH)        // 256 chunks per batch
#define GPB 16            // chains (16-lane groups) per 256-thread block
#define ROWB 72           // floats per 4-row block: 64 data + 8 pad (8 mod 32 banks)
#define MATS (4*ROWB)     // 288 floats per matrix buffer
#define LGS (2*MATS + 8)  // 584 floats per group; 584 % 32 == 8 -> group bank shift
#define BX 0
#define BY MATS
#define NA 128            // spectral-norm table size over [0, pi)
#define PI_F 3.14159265358979f

// Wave-synchronous LDS fence.
#define WSYNC() asm volatile("s_waitcnt lgkmcnt(0)" ::: "memory")

#define MM_FMA(A_, B0_, B1_, B2_, B3_, base) \
  acc[base+0] = fmaf(A_.w, B3_.x, fmaf(A_.z, B2_.x, fmaf(A_.y, B1_.x, fmaf(A_.x, B0_.x, acc[base+0])))); \
  acc[base+1] = fmaf(A_.w, B3_.y, fmaf(A_.z, B2_.y, fmaf(A_.y, B1_.y, fmaf(A_.x, B0_.y, acc[base+1])))); \
  acc[base+2] = fmaf(A_.w, B3_.z, fmaf(A_.z, B2_.z, fmaf(A_.y, B1_.z, fmaf(A_.x, B0_.z, acc[base+2])))); \
  acc[base+3] = fmaf(A_.w, B3_.w, fmaf(A_.z, B2_.w, fmaf(A_.y, B1_.w, fmaf(A_.x, B0_.w, acc[base+3]))));

// Layout: element (row,col): q=row>>2, rr=row&3, gc=col>>2 stored at
// q*ROWB + rr*16 + ((gc^q)<<2) + (col&3).  Reads and stores are bank-uniform.
template<bool CLR>
__device__ __forceinline__ void mmg(float acc[16], const float* sb, int offA, int offB,
                                    const int xA[4], const int xB[4], int trR) {
  if (CLR) {
#pragma unroll
    for (int e = 0; e < 16; ++e) acc[e] = 0.f;
  }
#pragma unroll
  for (int kk = 0; kk < 4; ++kk) {
    const float* pa = sb + offA + trR + xA[kk];
    const float* pb = sb + offB + kk*ROWB + xB[kk];
    float4 a0 = *(const float4*)(pa +  0);
    float4 a1 = *(const float4*)(pa + 16);
    float4 a2 = *(const float4*)(pa + 32);
    float4 a3 = *(const float4*)(pa + 48);
    float4 b0 = *(const float4*)(pb +  0);
    float4 b1 = *(const float4*)(pb + 16);
    float4 b2 = *(const float4*)(pb + 32);
    float4 b3 = *(const float4*)(pb + 48);
    MM_FMA(a0, b0, b1, b2, b3, 0)
    MM_FMA(a1, b0, b1, b2, b3, 4)
    MM_FMA(a2, b0, b1, b2, b3, 8)
    MM_FMA(a3, b0, b1, b2, b3, 12)
  }
}

__device__ __forceinline__ void st4(float* sb, int offD, const float v[16], int trR, int xD) {
  float* p = sb + offD + trR + xD;
#pragma unroll
  for (int rr = 0; rr < 4; ++rr)
    *(float4*)(p + rr*16) = make_float4(v[rr*4+0], v[rr*4+1], v[rr*4+2], v[rr*4+3]);
}

// k0: spectral-norm table rho(theta)=||cos*S1+sin*S2||_2 via power iteration.
__global__ __launch_bounds__(128) void k0_spec(const float* __restrict__ A1,
                                               const float* __restrict__ A2,
                                               float* __restrict__ ws) {
  __shared__ float S1[256], S2[256];
  const int tid = threadIdx.x;
  for (int e = tid; e < 256; e += 128) {
    int i_ = e >> 4, j_ = e & 15;
    S1[e] = A1[i_*16+j_] - A1[j_*16+i_];
    S2[e] = A2[i_*16+j_] - A2[j_*16+i_];
  }
  __syncthreads();
  const float th = (float)tid * (PI_F / NA);
  const float c = cosf(th), s = sinf(th);
  float v[16];
  float n2 = 0.f;
#pragma unroll
  for (int j = 0; j < 16; ++j) { v[j] = sinf(1.7f*(float)(j+1) + th) + 0.25f; n2 += v[j]*v[j]; }
  float inv = rsqrtf(n2);
#pragma unroll
  for (int j = 0; j < 16; ++j) v[j] *= inv;
  float lam = 0.f;
  for (int it = 0; it < 14; ++it) {
    float w[16];
#pragma unroll
    for (int i = 0; i < 16; ++i) {
      float a1 = 0.f, a2 = 0.f;
#pragma unroll
      for (int j = 0; j < 16; ++j) { a1 = fmaf(S1[i*16+j], v[j], a1); a2 = fmaf(S2[i*16+j], v[j], a2); }
      w[i] = c*a1 + s*a2;
    }
    n2 = 0.f;
#pragma unroll
    for (int i = 0; i < 16; ++i) n2 += w[i]*w[i];
    lam = sqrtf(n2);
    inv = (lam > 1e-20f) ? 1.f/lam : 0.f;
#pragma unroll
    for (int i = 0; i < 16; ++i) v[i] = w[i]*inv;
  }
  ws[tid] = lam * 1.05f;   // safety: power-iter underestimates; half-bin drift
}

// k1: per-chunk local scan, one chain per 16-lane group, zero barriers in loop.
__global__ __launch_bounds__(256, 4) void k1_chunk(const float* __restrict__ Z,
                                                   const float* __restrict__ A1,
                                                   const float* __restrict__ A2,
                                                   const float* __restrict__ ws,
                                                   float* __restrict__ Aout)
{
  __shared__ __align__(16) float lds[GPB * LGS];
  __shared__ float rhos[NA];
  const int tid = threadIdx.x;
  const int g   = tid >> 4;
  const int u   = tid & 15;
  const int tr  = u >> 2;
  const int tc  = u & 3;
  const int gw  = (tid & 63) >> 4;
  const int trR = tr * ROWB;

  if (tid < NA) rhos[tid] = ws[tid];
  __syncthreads();

  float* sb = lds + g * LGS;
  const int xA[4] = { ((0^tr)<<2), ((1^tr)<<2), ((2^tr)<<2), ((3^tr)<<2) };
  const int xB[4] = { ((tc^0)<<2), ((tc^1)<<2), ((tc^2)<<2), ((tc^3)<<2) };
  const int xD    = ((tc^tr)<<2);

  const int cid    = blockIdx.x * GPB + g;
  const int b      = cid >> 8;          // / KC  (KC = 256)
  const int kchunk = cid & (KC-1);
  const int t0     = kchunk * CH;

  const float trtc = (tr == tc) ? 1.f : 0.f;
  float s1t[16], s2t[16], idt[16];
#pragma unroll
  for (int rr = 0; rr < 4; ++rr)
#pragma unroll
    for (int cc = 0; cc < 4; ++cc) {
      int r_ = 4*tr + rr, c_ = 4*tc + cc;
      s1t[rr*4+cc] = A1[r_*16 + c_] - A1[c_*16 + r_];
      s2t[rr*4+cc] = A2[r_*16 + c_] - A2[c_*16 + r_];
      idt[rr*4+cc] = (rr == cc) ? trtc : 0.f;
    }

  float2 za = *(const float2*)&Z[(size_t)(b*NT + t0 + u) * 2];

  float lt[16], acc[16], gt[16], g2t[16], g3t[16], g4t[16];
#pragma unroll
  for (int e = 0; e < 16; ++e) lt[e] = idt[e];

  const float C3 = 1.f/6.f,   C4 = 1.f/24.f,   C5 = 1.f/120.f,
              C6 = 1.f/720.f, C7 = 1.f/5040.f, C8 = 1.f/40320.f;

  for (int tt = 0; tt < CH; ++tt) {
    const int t = t0 + tt;
    const size_t obase = (size_t)(b*NT + t) * 256 + (size_t)(tr*64) + 4*tc;
    if (kchunk == 0 && tt == 0) {
#pragma unroll
      for (int rr = 0; rr < 4; ++rr)
        *(float4*)&Aout[obase + rr*16] = make_float4(idt[rr*4+0], idt[rr*4+1], idt[rr*4+2], idt[rr*4+3]);
      continue;
    }
    const int src = (gw << 4) + tt;
    float z1 = __shfl(za.x, src);
    float z2 = __shfl(za.y, src);

    // exact spectral norm: ||z1*S1+z2*S2||_2 = r * rho(theta)
    float r_  = sqrtf(z1*z1 + z2*z2);
    float th  = atan2f(z2, z1);
    if (th < 0.f) th += PI_F;
    int   idx = ((int)(th * ((float)NA / PI_F) + 0.5f)) & (NA - 1);
    const float nrm = r_ * rhos[idx];
    int s = 0;
    if (nrm > 1.0f) s = (int)ceilf(log2f(nrm));     // scale to ||.|| <= 1.0
    const float scl = exp2f(-(float)s);
    z1 *= scl; z2 *= scl;

#pragma unroll
    for (int e = 0; e < 16; ++e) gt[e] = z1*s1t[e] + z2*s2t[e];
    st4(sb, BX, gt, trR, xD);  WSYNC();

    mmg<true>(acc, sb, BX, BX, xA, xB, trR);           // G2
#pragma unroll
    for (int e = 0; e < 16; ++e) g2t[e] = acc[e];
    st4(sb, BY, g2t, trR, xD); WSYNC();

    mmg<true>(g3t, sb, BY, BX, xA, xB, trR);           // G3 = G2*G
    mmg<true>(g4t, sb, BY, BY, xA, xB, trR);           // G4 = G2*G2
    st4(sb, BX, g4t, trR, xD);                         // BX := G4 (G dead)
#pragma unroll
    for (int e = 0; e < 16; ++e) acc[e] = C5*gt[e] + C6*g2t[e] + C7*g3t[e] + C8*g4t[e];
    st4(sb, BY, acc, trR, xD);                         // BY := U (G2 dead, in regs)
    WSYNC();

#pragma unroll
    for (int e = 0; e < 16; ++e)
      acc[e] = idt[e] + gt[e] + 0.5f*g2t[e] + C3*g3t[e] + C4*g4t[e];
    mmg<false>(acc, sb, BX, BY, xA, xB, trR);          // E = P1 + G4*U
    int cur = BY, oth = BX;
    st4(sb, cur, acc, trR, xD); WSYNC();

    for (int q = 0; q < s; ++q) {
      mmg<true>(acc, sb, cur, cur, xA, xB, trR);
      st4(sb, oth, acc, trR, xD); WSYNC();
      int tmp = cur; cur = oth; oth = tmp;
    }

    st4(sb, oth, lt, trR, xD); WSYNC();
    mmg<true>(acc, sb, oth, cur, xA, xB, trR);         // Lnew = L @ E
#pragma unroll
    for (int e = 0; e < 16; ++e) lt[e] = acc[e];

#pragma unroll
    for (int rr = 0; rr < 4; ++rr)
      *(float4*)&Aout[obase + rr*16] = make_float4(lt[rr*4+0], lt[rr*4+1], lt[rr*4+2], lt[rr*4+3]);
  }
}

// k2a: per (b, sub-group of 16 chunks): exclusive partial carries -> Binv[b,k*CH],
// sub-group total -> Binv[b, sb*256+1].
__global__ __launch_bounds__(256) void k2a(const float* __restrict__ Aout,
                                           float* __restrict__ Binv) {
  __shared__ float Cy[256], Lt[256];
  const int tid = threadIdx.x, i = tid >> 4, j = tid & 15;
  const int b = blockIdx.x >> 4, sb = blockIdx.x & 15;
  Cy[tid] = (i == j) ? 1.f : 0.f;
  float nxt = Aout[((size_t)(b*NT + (sb*16)*CH + CH - 1))*256 + tid];
  __syncthreads();
  for (int q = 0; q < 16; ++q) {
    const int k = sb*16 + q;
    Binv[((size_t)(b*NT + k*CH))*256 + tid] = Cy[tid];
    Lt[tid] = nxt;
    __syncthreads();
    if (q < 15) nxt = Aout[((size_t)(b*NT + (k+1)*CH + CH - 1))*256 + tid];
    float a2 = 0.f;
#pragma unroll
    for (int m = 0; m < 16; ++m) a2 = fmaf(Cy[i*16+m], Lt[m*16+j], a2);
    __syncthreads();
    Cy[tid] = a2;
    __syncthreads();
  }
  Binv[((size_t)(b*NT + sb*256 + 1))*256 + tid] = Cy[tid];
}

// k2b: per batch: exclusive scan over 16 sub-group totals -> Binv[b, sb*256+2].
__global__ __launch_bounds__(256) void k2b(float* __restrict__ Binv) {
  __shared__ float Cy[256], Lt[256];
  const int tid = threadIdx.x, i = tid >> 4, j = tid & 15;
  const int b = blockIdx.x;
  Cy[tid] = (i == j) ? 1.f : 0.f;
  float nxt = Binv[((size_t)(b*NT + 1))*256 + tid];
  __syncthreads();
  for (int sb2 = 0; sb2 < 16; ++sb2) {
    Binv[((size_t)(b*NT + sb2*256 + 2))*256 + tid] = Cy[tid];
    Lt[tid] = nxt;
    __syncthreads();
    if (sb2 < 15) nxt = Binv[((size_t)(b*NT + (sb2+1)*256 + 1))*256 + tid];
    float a2 = 0.f;
#pragma unroll
    for (int m = 0; m < 16; ++m) a2 = fmaf(Cy[i*16+m], Lt[m*16+j], a2);
    __syncthreads();
    Cy[tid] = a2;
    __syncthreads();
  }
}

// k2c: full carry = supercarry @ partial, written back to Binv[b,k*CH].
__global__ __launch_bounds__(256) void k2c(float* __restrict__ Binv) {
  __shared__ float Sup[256], Lt[256];
  const int tid = threadIdx.x, i = tid >> 4, j = tid & 15;
  const int b = blockIdx.x >> 4, sb = blockIdx.x & 15;
  Sup[tid] = Binv[((size_t)(b*NT + sb*256 + 2))*256 + tid];
  float nxt = Binv[((size_t)(b*NT + (sb*16)*CH))*256 + tid];
  __syncthreads();
  for (int q = 0; q < 16; ++q) {
    const int k = sb*16 + q;
    Lt[tid] = nxt;
    __syncthreads();
    if (q < 15) nxt = Binv[((size_t)(b*NT + (k+1)*CH))*256 + tid];
    float a2 = 0.f;
#pragma unroll
    for (int m = 0; m < 16; ++m) a2 = fmaf(Sup[i*16+m], Lt[m*16+j], a2);
    Binv[((size_t)(b*NT + k*CH))*256 + tid] = a2;
    __syncthreads();
  }
}

// k3: A[t] = Carry @ L[t]; B_inv[t] = A[t]^T (A orthogonal).
__global__ __launch_bounds__(256) void k3_apply(float* __restrict__ Aout,
                                                float* __restrict__ Binv)
{
  __shared__ float Cy[256], Lt[256], Tr[16*17];
  const int tid = threadIdx.x, i = tid >> 4, j = tid & 15;
  const int b = blockIdx.x >> 8;          // / KC
  const int kchunk = blockIdx.x & (KC-1);
  const int t0 = kchunk * CH;
  Cy[tid] = Binv[((size_t)(b*NT + t0))*256 + tid];
  __syncthreads();
  for (int t = t0; t < t0 + CH; ++t) {
    Lt[tid] = Aout[((size_t)(b*NT + t))*256 + tid];
    __syncthreads();
    float a2 = 0.f;
#pragma unroll
    for (int m = 0; m < 16; ++m) a2 = fmaf(Cy[i*16+m], Lt[m*16+j], a2);
    Aout[((size_t)(b*NT + t))*256 + tid] = a2;
    Tr[i*17 + j] = a2;
    __syncthreads();
    Binv[((size_t)(b*NT + t))*256 + tid] = Tr[j*17 + i];
    __syncthreads();
  }
}

extern "C" void kernel_launch(void* const* d_in, const int* in_sizes, int n_in,
                              void* d_out, int out_size, void* d_ws, size_t ws_size,
                              hipStream_t stream) {
  const float* Z  = (const float*)d_in[0];
  const float* A1 = (const float*)d_in[1];
  const float* A2 = (const float*)d_in[2];
  float* ws   = (float*)d_ws;
  float* Aout = (float*)d_out;
  float* Binv = Aout + (size_t)NB * NT * 256;

  k0_spec<<<1, 128, 0, stream>>>(A1, A2, ws);
  k1_chunk<<<NB * KC / GPB, 256, 0, stream>>>(Z, A1, A2, ws, Aout);
  k2a<<<NB * 16, 256, 0, stream>>>(Aout, Binv);
  k2b<<<NB, 256, 0, stream>>>(Binv);
  k2c<<<NB * 16, 256, 0, stream>>>(Binv);
  k3_apply<<<NB * KC, 256, 0, stream>>>(Aout, Binv);
}

// Round 4
// 633.603 us; speedup vs baseline: 1.0906x; 1.0906x over previous
//
#include <hip/hip_runtime.h>

#define NB 64
#define NT 4096
#define CH 16
#define KC (NT/CH)        // 256 chunks per batch
#define GPB 16            // chains (16-lane groups) per 256-thread block
#define ROWB 72           // floats per 4-row block: 64 data + 8 pad (8 mod 32 banks)
#define MATS (4*ROWB)     // 288 floats per matrix buffer
#define LGS (2*MATS + 8)  // 584 floats per group; 584 % 32 == 8 -> group bank shift
#define BX 0
#define BY MATS
#define NA 128            // spectral-norm table size over [0, pi)
#define PI_F 3.14159265358979f

// Wave-synchronous LDS fence (16-lane groups are sub-wave -> lockstep).
#define WSYNC() asm volatile("s_waitcnt lgkmcnt(0)" ::: "memory")

#define MM_FMA(A_, B0_, B1_, B2_, B3_, base) \
  acc[base+0] = fmaf(A_.w, B3_.x, fmaf(A_.z, B2_.x, fmaf(A_.y, B1_.x, fmaf(A_.x, B0_.x, acc[base+0])))); \
  acc[base+1] = fmaf(A_.w, B3_.y, fmaf(A_.z, B2_.y, fmaf(A_.y, B1_.y, fmaf(A_.x, B0_.y, acc[base+1])))); \
  acc[base+2] = fmaf(A_.w, B3_.z, fmaf(A_.z, B2_.z, fmaf(A_.y, B1_.z, fmaf(A_.x, B0_.z, acc[base+2])))); \
  acc[base+3] = fmaf(A_.w, B3_.w, fmaf(A_.z, B2_.w, fmaf(A_.y, B1_.w, fmaf(A_.x, B0_.w, acc[base+3]))));

// Layout: element (row,col): q=row>>2, rr=row&3, gc=col>>2 stored at
// q*ROWB + rr*16 + ((gc^q)<<2) + (col&3).
template<bool CLR>
__device__ __forceinline__ void mmg(float acc[16], const float* sb, int offA, int offB,
                                    const int xA[4], const int xB[4], int trR) {
  if (CLR) {
#pragma unroll
    for (int e = 0; e < 16; ++e) acc[e] = 0.f;
  }
#pragma unroll
  for (int kk = 0; kk < 4; ++kk) {
    const float* pa = sb + offA + trR + xA[kk];
    const float* pb = sb + offB + kk*ROWB + xB[kk];
    float4 a0 = *(const float4*)(pa +  0);
    float4 a1 = *(const float4*)(pa + 16);
    float4 a2 = *(const float4*)(pa + 32);
    float4 a3 = *(const float4*)(pa + 48);
    float4 b0 = *(const float4*)(pb +  0);
    float4 b1 = *(const float4*)(pb + 16);
    float4 b2 = *(const float4*)(pb + 32);
    float4 b3 = *(const float4*)(pb + 48);
    MM_FMA(a0, b0, b1, b2, b3, 0)
    MM_FMA(a1, b0, b1, b2, b3, 4)
    MM_FMA(a2, b0, b1, b2, b3, 8)
    MM_FMA(a3, b0, b1, b2, b3, 12)
  }
}

__device__ __forceinline__ void st4(float* sb, int offD, const float v[16], int trR, int xD) {
  float* p = sb + offD + trR + xD;
#pragma unroll
  for (int rr = 0; rr < 4; ++rr)
    *(float4*)(p + rr*16) = make_float4(v[rr*4+0], v[rr*4+1], v[rr*4+2], v[rr*4+3]);
}

// k0: spectral-norm table rho(theta)=||cos*S1+sin*S2||_2 via power iteration.
__global__ __launch_bounds__(128) void k0_spec(const float* __restrict__ A1,
                                               const float* __restrict__ A2,
                                               float* __restrict__ ws) {
  __shared__ float S1[256], S2[256];
  const int tid = threadIdx.x;
  for (int e = tid; e < 256; e += 128) {
    int i_ = e >> 4, j_ = e & 15;
    S1[e] = A1[i_*16+j_] - A1[j_*16+i_];
    S2[e] = A2[i_*16+j_] - A2[j_*16+i_];
  }
  __syncthreads();
  const float th = (float)tid * (PI_F / NA);
  const float c = cosf(th), s = sinf(th);
  float v[16];
  float n2 = 0.f;
#pragma unroll
  for (int j = 0; j < 16; ++j) { v[j] = sinf(1.7f*(float)(j+1) + th) + 0.25f; n2 += v[j]*v[j]; }
  float inv = rsqrtf(n2);
#pragma unroll
  for (int j = 0; j < 16; ++j) v[j] *= inv;
  float lam = 0.f;
  for (int it = 0; it < 14; ++it) {
    float w[16];
#pragma unroll
    for (int i = 0; i < 16; ++i) {
      float a1 = 0.f, a2 = 0.f;
#pragma unroll
      for (int j = 0; j < 16; ++j) { a1 = fmaf(S1[i*16+j], v[j], a1); a2 = fmaf(S2[i*16+j], v[j], a2); }
      w[i] = c*a1 + s*a2;
    }
    n2 = 0.f;
#pragma unroll
    for (int i = 0; i < 16; ++i) n2 += w[i]*w[i];
    lam = sqrtf(n2);
    inv = (lam > 1e-20f) ? 1.f/lam : 0.f;
#pragma unroll
    for (int i = 0; i < 16; ++i) v[i] = w[i]*inv;
  }
  ws[tid] = lam * 1.05f;
}

// k1: per-chunk local scan; streaming p/u accumulation keeps live set <= ~112 floats.
__global__ __launch_bounds__(256, 3) void k1_chunk(const float* __restrict__ Z,
                                                   const float* __restrict__ A1,
                                                   const float* __restrict__ A2,
                                                   const float* __restrict__ ws,
                                                   float* __restrict__ Aout)
{
  __shared__ __align__(16) float lds[GPB * LGS];
  __shared__ float rhos[NA];
  const int tid = threadIdx.x;
  const int g   = tid >> 4;
  const int u   = tid & 15;
  const int tr  = u >> 2;
  const int tc  = u & 3;
  const int gw  = (tid & 63) >> 4;
  const int trR = tr * ROWB;

  if (tid < NA) rhos[tid] = ws[tid];
  __syncthreads();

  float* sb = lds + g * LGS;
  const int xA[4] = { ((0^tr)<<2), ((1^tr)<<2), ((2^tr)<<2), ((3^tr)<<2) };
  const int xB[4] = { ((tc^0)<<2), ((tc^1)<<2), ((tc^2)<<2), ((tc^3)<<2) };
  const int xD    = ((tc^tr)<<2);

  const int cid    = blockIdx.x * GPB + g;
  const int b      = cid >> 8;          // / KC  (KC = 256)
  const int kchunk = cid & (KC-1);
  const int t0     = kchunk * CH;

  const float trtc = (tr == tc) ? 1.f : 0.f;
  float s1t[16], s2t[16];
#pragma unroll
  for (int rr = 0; rr < 4; ++rr)
#pragma unroll
    for (int cc = 0; cc < 4; ++cc) {
      int r_ = 4*tr + rr, c_ = 4*tc + cc;
      s1t[rr*4+cc] = A1[r_*16 + c_] - A1[c_*16 + r_];
      s2t[rr*4+cc] = A2[r_*16 + c_] - A2[c_*16 + r_];
    }

  float2 za = *(const float2*)&Z[(size_t)(b*NT + t0 + u) * 2];

  float lt[16], acc[16], gt[16], pp[16], uu[16];
#pragma unroll
  for (int rr = 0; rr < 4; ++rr)
#pragma unroll
    for (int cc = 0; cc < 4; ++cc) lt[rr*4+cc] = (rr == cc) ? trtc : 0.f;

  const float C3 = 1.f/6.f,   C4 = 1.f/24.f,   C5 = 1.f/120.f,
              C6 = 1.f/720.f, C7 = 1.f/5040.f, C8 = 1.f/40320.f;

  for (int tt = 0; tt < CH; ++tt) {
    const int t = t0 + tt;
    const size_t obase = (size_t)(b*NT + t) * 256 + (size_t)(tr*64) + 4*tc;
    if (kchunk == 0 && tt == 0) {
#pragma unroll
      for (int rr = 0; rr < 4; ++rr)
        *(float4*)&Aout[obase + rr*16] =
          make_float4(lt[rr*4+0], lt[rr*4+1], lt[rr*4+2], lt[rr*4+3]);
      continue;
    }
    const int src = (gw << 4) + tt;
    float z1 = __shfl(za.x, src);
    float z2 = __shfl(za.y, src);

    float r_  = sqrtf(z1*z1 + z2*z2);
    float th  = atan2f(z2, z1);
    if (th < 0.f) th += PI_F;
    int   idx = ((int)(th * ((float)NA / PI_F) + 0.5f)) & (NA - 1);
    const float nrm = r_ * rhos[idx];
    int s = 0;
    if (nrm > 1.0f) s = (int)ceilf(log2f(nrm));
    const float scl = exp2f(-(float)s);
    z1 *= scl; z2 *= scl;

#pragma unroll
    for (int e = 0; e < 16; ++e) gt[e] = z1*s1t[e] + z2*s2t[e];
    st4(sb, BX, gt, trR, xD);  WSYNC();

    mmg<true>(acc, sb, BX, BX, xA, xB, trR);            // G2
    st4(sb, BY, acc, trR, xD);
#pragma unroll
    for (int e = 0; e < 16; ++e) {
      pp[e] = gt[e] + 0.5f*acc[e];
      uu[e] = C5*gt[e] + C6*acc[e];
    }
    pp[0] += trtc; pp[5] += trtc; pp[10] += trtc; pp[15] += trtc;       // + I
    uu[0] += C4*trtc; uu[5] += C4*trtc; uu[10] += C4*trtc; uu[15] += C4*trtc;
    WSYNC();

    mmg<true>(acc, sb, BY, BX, xA, xB, trR);            // G3 = G2*G
#pragma unroll
    for (int e = 0; e < 16; ++e) { pp[e] += C3*acc[e]; uu[e] += C7*acc[e]; }
    mmg<true>(acc, sb, BY, BY, xA, xB, trR);            // G4 = G2*G2
#pragma unroll
    for (int e = 0; e < 16; ++e) uu[e] += C8*acc[e];
    st4(sb, BX, acc, trR, xD);                          // BX := G4
    st4(sb, BY, uu, trR, xD);                           // BY := U
    WSYNC();

    mmg<false>(pp, sb, BX, BY, xA, xB, trR);            // E = P1 + G4*U
    int cur = BY, oth = BX;
    st4(sb, cur, pp, trR, xD); WSYNC();

    for (int q = 0; q < s; ++q) {
      mmg<true>(acc, sb, cur, cur, xA, xB, trR);
      st4(sb, oth, acc, trR, xD); WSYNC();
      int tmp = cur; cur = oth; oth = tmp;
    }

    st4(sb, oth, lt, trR, xD); WSYNC();
    mmg<true>(acc, sb, oth, cur, xA, xB, trR);          // Lnew = L @ E
#pragma unroll
    for (int e = 0; e < 16; ++e) lt[e] = acc[e];

#pragma unroll
    for (int rr = 0; rr < 4; ++rr)
      *(float4*)&Aout[obase + rr*16] =
        make_float4(lt[rr*4+0], lt[rr*4+1], lt[rr*4+2], lt[rr*4+3]);
  }
}

// k2a: per (b, subgroup of 16 chunks): exclusive partial carries -> Binv[b,k*CH],
// subgroup total -> Binv[b, sb*256+1].
__global__ __launch_bounds__(256) void k2a(const float* __restrict__ Aout,
                                           float* __restrict__ Binv) {
  __shared__ float Cy[256], Lt[256];
  const int tid = threadIdx.x, i = tid >> 4, j = tid & 15;
  const int b = blockIdx.x >> 4, sb = blockIdx.x & 15;
  Cy[tid] = (i == j) ? 1.f : 0.f;
  float nxt = Aout[((size_t)(b*NT + (sb*16)*CH + CH - 1))*256 + tid];
  __syncthreads();
  for (int q = 0; q < 16; ++q) {
    const int k = sb*16 + q;
    Binv[((size_t)(b*NT + k*CH))*256 + tid] = Cy[tid];
    Lt[tid] = nxt;
    __syncthreads();
    if (q < 15) nxt = Aout[((size_t)(b*NT + (k+1)*CH + CH - 1))*256 + tid];
    float a2 = 0.f;
#pragma unroll
    for (int m = 0; m < 16; ++m) a2 = fmaf(Cy[i*16+m], Lt[m*16+j], a2);
    __syncthreads();
    Cy[tid] = a2;
    __syncthreads();
  }
  Binv[((size_t)(b*NT + sb*256 + 1))*256 + tid] = Cy[tid];
}

// k2b: per batch: exclusive scan over 16 subgroup totals -> supercarry at Binv[b,sb*256+2].
__global__ __launch_bounds__(256) void k2b(float* __restrict__ Binv) {
  __shared__ float Cy[256], Lt[256];
  const int tid = threadIdx.x, i = tid >> 4, j = tid & 15;
  const int b = blockIdx.x;
  Cy[tid] = (i == j) ? 1.f : 0.f;
  float nxt = Binv[((size_t)(b*NT + 1))*256 + tid];
  __syncthreads();
  for (int sb2 = 0; sb2 < 16; ++sb2) {
    Binv[((size_t)(b*NT + sb2*256 + 2))*256 + tid] = Cy[tid];
    Lt[tid] = nxt;
    __syncthreads();
    if (sb2 < 15) nxt = Binv[((size_t)(b*NT + (sb2+1)*256 + 1))*256 + tid];
    float a2 = 0.f;
#pragma unroll
    for (int m = 0; m < 16; ++m) a2 = fmaf(Cy[i*16+m], Lt[m*16+j], a2);
    __syncthreads();
    Cy[tid] = a2;
    __syncthreads();
  }
}

// k3: group-based fixup. W = Super * Partial (once per chain, kept in LDS);
// per t: A[t] = W @ L[t]  (write), Binv[t] = A[t]^T via LDS transpose.
// All cross-block temporaries were written by k2a/k2b; every read this block
// does is inside its own output range -> race-free.
__global__ __launch_bounds__(256) void k3_apply(float* __restrict__ Aout,
                                               float* __restrict__ Binv)
{
  __shared__ __align__(16) float lds[GPB * LGS];
  __shared__ float SupL[256];
  const int tid = threadIdx.x;
  const int g   = tid >> 4;
  const int u   = tid & 15;
  const int tr  = u >> 2;
  const int tc  = u & 3;
  const int trR = tr * ROWB;
  float* sb_ = lds + g * LGS;
  const int xA[4] = { ((0^tr)<<2), ((1^tr)<<2), ((2^tr)<<2), ((3^tr)<<2) };
  const int xB[4] = { ((tc^0)<<2), ((tc^1)<<2), ((tc^2)<<2), ((tc^3)<<2) };
  const int xD    = ((tc^tr)<<2);

  const int b   = blockIdx.x >> 4;
  const int sbq = blockIdx.x & 15;
  const int k   = sbq*16 + g;
  const int t0  = k * CH;

  SupL[tid] = Binv[((size_t)(b*NT + sbq*256 + 2))*256 + tid];
  // stage partial carry P_k into BX (swizzled)
  {
    const float* srcp = &Binv[((size_t)(b*NT + k*CH))*256];
#pragma unroll
    for (int rr = 0; rr < 4; ++rr) {
      float4 v = *(const float4*)&srcp[rr*64 + 4*u];
      *(float4*)&sb_[BX + rr*ROWB + tr*16 + ((tc^rr)<<2)] = v;
    }
  }
  __syncthreads();

  // wt = Sup @ P   (A-operand rows from linear SupL, B from swizzled BX)
  float wt[16];
  {
    float* acc = wt;
#pragma unroll
    for (int e = 0; e < 16; ++e) acc[e] = 0.f;
#pragma unroll
    for (int kk = 0; kk < 4; ++kk) {
      const float* pb = sb_ + BX + kk*ROWB + xB[kk];
      float4 b0 = *(const float4*)(pb +  0);
      float4 b1 = *(const float4*)(pb + 16);
      float4 b2 = *(const float4*)(pb + 32);
      float4 b3 = *(const float4*)(pb + 48);
      float4 a0 = *(const float4*)&SupL[(4*tr+0)*16 + 4*kk];
      float4 a1 = *(const float4*)&SupL[(4*tr+1)*16 + 4*kk];
      float4 a2 = *(const float4*)&SupL[(4*tr+2)*16 + 4*kk];
      float4 a3 = *(const float4*)&SupL[(4*tr+3)*16 + 4*kk];
      MM_FMA(a0, b0, b1, b2, b3, 0)
      MM_FMA(a1, b0, b1, b2, b3, 4)
      MM_FMA(a2, b0, b1, b2, b3, 8)
      MM_FMA(a3, b0, b1, b2, b3, 12)
    }
  }
  st4(sb_, BY, wt, trR, xD);   // BY := W for the whole loop
  WSYNC();

  float acc[16];
  for (int tt = 0; tt < CH; ++tt) {
    const size_t base = ((size_t)(b*NT + t0 + tt))*256;
    // stage L[t] into BX
#pragma unroll
    for (int rr = 0; rr < 4; ++rr) {
      float4 v = *(const float4*)&Aout[base + rr*64 + 4*u];
      *(float4*)&sb_[BX + rr*ROWB + tr*16 + ((tc^rr)<<2)] = v;
    }
    WSYNC();
    mmg<true>(acc, sb_, BY, BX, xA, xB, trR);           // A = W @ L
    const size_t obase = base + (size_t)(tr*64) + 4*tc;
#pragma unroll
    for (int rr = 0; rr < 4; ++rr)
      *(float4*)&Aout[obase + rr*16] =
        make_float4(acc[rr*4+0], acc[rr*4+1], acc[rr*4+2], acc[rr*4+3]);
    // transpose via BX (L dead)
    st4(sb_, BX, acc, trR, xD); WSYNC();
    const float* pt = sb_ + BX + tc*ROWB + ((tr^tc)<<2);
    float4 f0 = *(const float4*)(pt +  0);
    float4 f1 = *(const float4*)(pt + 16);
    float4 f2 = *(const float4*)(pt + 32);
    float4 f3 = *(const float4*)(pt + 48);
    *(float4*)&Binv[obase +  0] = make_float4(f0.x, f1.x, f2.x, f3.x);
    *(float4*)&Binv[obase + 16] = make_float4(f0.y, f1.y, f2.y, f3.y);
    *(float4*)&Binv[obase + 32] = make_float4(f0.z, f1.z, f2.z, f3.z);
    *(float4*)&Binv[obase + 48] = make_float4(f0.w, f1.w, f2.w, f3.w);
    WSYNC();
  }
}

extern "C" void kernel_launch(void* const* d_in, const int* in_sizes, int n_in,
                              void* d_out, int out_size, void* d_ws, size_t ws_size,
                              hipStream_t stream) {
  const float* Z  = (const float*)d_in[0];
  const float* A1 = (const float*)d_in[1];
  const float* A2 = (const float*)d_in[2];
  float* ws   = (float*)d_ws;
  float* Aout = (float*)d_out;
  float* Binv = Aout + (size_t)NB * NT * 256;

  k0_spec<<<1, 128, 0, stream>>>(A1, A2, ws);
  k1_chunk<<<NB * KC / GPB, 256, 0, stream>>>(Z, A1, A2, ws, Aout);
  k2a<<<NB * 16, 256, 0, stream>>>(Aout, Binv);
  k2b<<<64, 256, 0, stream>>>(Binv);
  k3_apply<<<NB * 16, 256, 0, stream>>>(Aout, Binv);
}